// Round 1
// baseline (1774.007 us; speedup 1.0000x reference)
//
#include <hip/hip_runtime.h>
#include <math.h>

#define Tt 32
#define Bb 64
#define Ss 64
#define Ee 512
#define Hh 1024
#define Vv 32000
#define LEc 32
#define G4H 4096
#define Mm 2048   // T*B rows

typedef __bf16 bf16x8 __attribute__((ext_vector_type(8)));
typedef float f32x4 __attribute__((ext_vector_type(4)));
typedef short short4v __attribute__((ext_vector_type(4)));

__device__ __forceinline__ short f2bf(float f){
  unsigned u = __builtin_bit_cast(unsigned, f);
  u += 0x7fffu + ((u >> 16) & 1u);
  return (short)(u >> 16);
}

// ---------------- hypernet: w_ih / w_hh generation (bf16 out) ----------------
__global__ __launch_bounds__(256) void k_hyper_w(
    const float* __restrict__ Wih, const float* __restrict__ bihv,
    const float* __restrict__ Whh, const float* __restrict__ bhhv,
    const float* __restrict__ lang_embed, const int* __restrict__ lang_idx,
    short* __restrict__ w_ih, short* __restrict__ w_hh)
{
  const long NIH = (long)G4H * Ee;              // 2,097,152 rows
  const long NALL = NIH + (long)G4H * Hh;       // + 4,194,304 rows
  long r = (long)blockIdx.x * 256 + threadIdx.x;
  if (r >= NALL) return;
  const float4* el4 = (const float4*)(lang_embed + (size_t)lang_idx[0] * LEc);
  float4 e[8];
  #pragma unroll
  for (int j = 0; j < 8; j++) e[j] = el4[j];
  const float4* W4; float bb; short* outp;
  if (r < NIH){ W4 = (const float4*)(Wih + r * LEc); bb = bihv[r]; outp = w_ih + r; }
  else { long rr = r - NIH; W4 = (const float4*)(Whh + rr * LEc); bb = bhhv[rr]; outp = w_hh + rr; }
  float acc = bb;
  #pragma unroll
  for (int j = 0; j < 8; j++){
    float4 w = W4[j];
    acc += w.x*e[j].x + w.y*e[j].y + w.z*e[j].z + w.w*e[j].w;
  }
  *outp = f2bf(acc);
}

// ---------------- hypernet: combined bias b_ih + b_hh (f32) ----------------
__global__ __launch_bounds__(256) void k_hyper_b(
    const float* __restrict__ Wbih, const float* __restrict__ bbih,
    const float* __restrict__ Wbhh, const float* __restrict__ bbhh,
    const float* __restrict__ lang_embed, const int* __restrict__ lang_idx,
    float* __restrict__ b_total)
{
  int u = blockIdx.x * 256 + threadIdx.x;
  if (u >= G4H) return;
  const float* el = lang_embed + (size_t)lang_idx[0] * LEc;
  float acc = bbih[u] + bbhh[u];
  #pragma unroll
  for (int j = 0; j < LEc; j++)
    acc += (Wbih[(size_t)u*LEc + j] + Wbhh[(size_t)u*LEc + j]) * el[j];
  b_total[u] = acc;
}

// ---------------- embedding gather -> bf16 ----------------
__global__ __launch_bounds__(256) void k_embed(
    const int* __restrict__ x, const float* __restrict__ vocab, short* __restrict__ emb)
{
  int tid = blockIdx.x * 256 + threadIdx.x;      // Mm*Ee/4 threads
  if (tid >= Mm * Ee / 4) return;
  int row = tid / (Ee / 4);
  int j4 = (tid % (Ee / 4)) * 4;
  int tok = x[row];
  float4 v = *(const float4*)(vocab + (size_t)tok * Ee + j4);
  short4v o = { f2bf(v.x), f2bf(v.y), f2bf(v.z), f2bf(v.w) };
  *(short4v*)(emb + (size_t)row * Ee + j4) = o;
}

// ---------------- generic f32 -> bf16 convert ----------------
__global__ __launch_bounds__(256) void k_f2bf(const float* __restrict__ in, short* __restrict__ out, long n4)
{
  long i = (long)blockIdx.x * 256 + threadIdx.x;
  if (i >= n4) return;
  float4 v = ((const float4*)in)[i];
  short4v o = { f2bf(v.x), f2bf(v.y), f2bf(v.z), f2bf(v.w) };
  ((short4v*)out)[i] = o;
}

// ---------------- Gx = emb @ w_ih^T + b_total  (M=2048, N=4096, K=512) ----------------
__global__ __launch_bounds__(256) void k_xgates(
    const short* __restrict__ emb, const short* __restrict__ w_ih,
    const float* __restrict__ b_total, float* __restrict__ Gx)
{
  int w = blockIdx.x * 4 + (threadIdx.x >> 6);   // 8192 waves
  int lane = threadIdx.x & 63;
  int mt = w >> 6;                               // 0..127
  int n0 = (w & 63) * 64;                        // 0..4032
  int ra = lane & 15, ko = (lane >> 4) * 8;
  f32x4 acc[4] = {{0,0,0,0},{0,0,0,0},{0,0,0,0},{0,0,0,0}};
  const short* Ap = emb  + (size_t)(mt*16 + ra) * Ee + ko;
  const short* Bp = w_ih + (size_t)(n0    + ra) * Ee + ko;
  for (int kk = 0; kk < Ee; kk += 32){
    bf16x8 a = *(const bf16x8*)(Ap + kk);
    #pragma unroll
    for (int j = 0; j < 4; j++){
      bf16x8 b = *(const bf16x8*)(Bp + (size_t)j*16*Ee + kk);
      acc[j] = __builtin_amdgcn_mfma_f32_16x16x32_bf16(a, b, acc[j], 0, 0, 0);
    }
  }
  int col = lane & 15, r0 = (lane >> 4) * 4;
  #pragma unroll
  for (int j = 0; j < 4; j++)
    #pragma unroll
    for (int i = 0; i < 4; i++){
      int m = mt*16 + r0 + i;
      int n = n0 + j*16 + col;
      Gx[(size_t)m * G4H + n] = acc[j][i] + b_total[n];
    }
}

// ---------------- init h (bf16) and c (f32) ----------------
__global__ __launch_bounds__(256) void k_init_hc(
    const float* __restrict__ h0, const float* __restrict__ c0,
    short* __restrict__ hbf, float* __restrict__ c)
{
  int i = blockIdx.x * 256 + threadIdx.x;
  if (i >= Bb * Hh) return;
  hbf[i] = f2bf(h0[i]);
  c[i] = c0[i];
}

// ---------------- one LSTM step: gates = Gx[t] + h @ w_hh^T ; elementwise ----------------
// grid 256 blocks x 256 threads. block -> (mt 0..3, ng 0..63). 4 waves split K=1024 into 4x256.
__global__ __launch_bounds__(256) void k_step(
    int t, const short* __restrict__ h_in, const short* __restrict__ w_hh,
    const float* __restrict__ Gx, float* __restrict__ c,
    short* __restrict__ h_out, float* __restrict__ rnn_out, short* __restrict__ concat)
{
  __shared__ float red[4][4][16][16];
  int mt = blockIdx.x >> 6;          // 0..3
  int n0 = (blockIdx.x & 63) * 16;   // 0..1008
  int wv = threadIdx.x >> 6;         // k-chunk 0..3
  int lane = threadIdx.x & 63;
  int ra = lane & 15, ko = (lane >> 4) * 8;
  f32x4 acc[4] = {{0,0,0,0},{0,0,0,0},{0,0,0,0},{0,0,0,0}};
  const short* Ap = h_in + (size_t)(mt*16 + ra) * Hh + wv*256 + ko;
  const short* Bp = w_hh + (size_t)(n0    + ra) * Hh + wv*256 + ko;
  #pragma unroll
  for (int kk = 0; kk < 256; kk += 32){
    bf16x8 a = *(const bf16x8*)(Ap + kk);
    #pragma unroll
    for (int g = 0; g < 4; g++){
      bf16x8 b = *(const bf16x8*)(Bp + (size_t)g*Hh*Hh + kk);
      acc[g] = __builtin_amdgcn_mfma_f32_16x16x32_bf16(a, b, acc[g], 0, 0, 0);
    }
  }
  int col = lane & 15, r0 = (lane >> 4) * 4;
  #pragma unroll
  for (int g = 0; g < 4; g++)
    #pragma unroll
    for (int i = 0; i < 4; i++)
      red[wv][g][r0 + i][col] = acc[g][i];
  __syncthreads();

  int r  = threadIdx.x >> 4;   // 0..15
  int cc = threadIdx.x & 15;
  int b  = mt*16 + r;
  int u  = n0 + cc;
  float gate[4];
  #pragma unroll
  for (int g = 0; g < 4; g++){
    float s = Gx[((size_t)t*Bb + b) * G4H + g*Hh + u];
    #pragma unroll
    for (int w2 = 0; w2 < 4; w2++) s += red[w2][g][r][cc];
    gate[g] = s;
  }
  float ig = 1.f / (1.f + expf(-gate[0]));
  float fg = 1.f / (1.f + expf(-gate[1]));
  float gg = tanhf(gate[2]);
  float og = 1.f / (1.f + expf(-gate[3]));
  size_t bu = (size_t)b * Hh + u;
  float cn = fg * c[bu] + ig * gg;
  c[bu] = cn;
  float hn = og * tanhf(cn);
  h_out[bu] = f2bf(hn);
  size_t row = (size_t)t * Bb + b;
  rnn_out[row * Hh + u] = hn;
  concat[row * (2*Hh) + Hh + u] = f2bf(hn);
}

// ---------------- scores + mask + softmax (wave per (t,b), lane = s) ----------------
__global__ __launch_bounds__(64) void k_scores(
    const float* __restrict__ rnn_out, const float* __restrict__ src,
    const int* __restrict__ src_len, float* __restrict__ attn)
{
  int t = blockIdx.x >> 6;
  int b = blockIdx.x & 63;
  int s = threadIdx.x;
  const float4* rp = (const float4*)(rnn_out + ((size_t)t*Bb + b) * Hh);
  const float4* sp = (const float4*)(src     + ((size_t)s*Bb + b) * Hh);
  float acc = 0.f;
  #pragma unroll 4
  for (int i = 0; i < Hh/4; i++){
    float4 rv = rp[i], sv = sp[i];
    acc += rv.x*sv.x + rv.y*sv.y + rv.z*sv.z + rv.w*sv.w;
  }
  if (s >= src_len[b]) acc = -1e30f;
  float mx = acc;
  for (int o = 32; o; o >>= 1) mx = fmaxf(mx, __shfl_xor(mx, o, 64));
  float p = expf(acc - mx);
  float sum = p;
  for (int o = 32; o; o >>= 1) sum += __shfl_xor(sum, o, 64);
  attn[((size_t)t*Bb + b) * Ss + s] = p / sum;
}

// ---------------- context = attn @ src  -> concat[:, 0:H] (bf16) ----------------
// block per (b, t-group of 8); 256 threads over H (4 floats each)
__global__ __launch_bounds__(256) void k_context(
    const float* __restrict__ attn, const float* __restrict__ src, short* __restrict__ concat)
{
  __shared__ float sat[8][64];
  int b  = blockIdx.x & 63;
  int t0 = (blockIdx.x >> 6) * 8;
  int tid = threadIdx.x;
  for (int i = tid; i < 8*64; i += 256){
    int ti = i >> 6, s = i & 63;
    sat[ti][s] = attn[((size_t)(t0 + ti)*Bb + b) * Ss + s];
  }
  __syncthreads();
  int h0 = tid * 4;
  float4 acc[8];
  #pragma unroll
  for (int i = 0; i < 8; i++) acc[i] = make_float4(0.f, 0.f, 0.f, 0.f);
  for (int s = 0; s < Ss; s++){
    float4 sv = *(const float4*)(src + ((size_t)s*Bb + b) * Hh + h0);
    #pragma unroll
    for (int i = 0; i < 8; i++){
      float a = sat[i][s];
      acc[i].x += a*sv.x; acc[i].y += a*sv.y; acc[i].z += a*sv.z; acc[i].w += a*sv.w;
    }
  }
  #pragma unroll
  for (int i = 0; i < 8; i++){
    size_t row = (size_t)(t0 + i)*Bb + b;
    short4v o = { f2bf(acc[i].x), f2bf(acc[i].y), f2bf(acc[i].z), f2bf(acc[i].w) };
    *(short4v*)(concat + row * (2*Hh) + h0) = o;
  }
}

// ---------------- attn_hidden = tanh(concat @ c2h_W^T + c2h_b)  (M=2048,N=1024,K=2048) ----------------
__global__ __launch_bounds__(256) void k_c2h(
    const short* __restrict__ concat, const short* __restrict__ Wc,
    const float* __restrict__ bc, short* __restrict__ attn_hidden)
{
  int w = blockIdx.x * 4 + (threadIdx.x >> 6);   // 2048 waves
  int lane = threadIdx.x & 63;
  int mt = w >> 4;                               // 0..127
  int n0 = (w & 15) * 64;                        // 0..960
  int ra = lane & 15, ko = (lane >> 4) * 8;
  f32x4 acc[4] = {{0,0,0,0},{0,0,0,0},{0,0,0,0},{0,0,0,0}};
  const short* Ap = concat + (size_t)(mt*16 + ra) * (2*Hh) + ko;
  const short* Bp = Wc     + (size_t)(n0    + ra) * (2*Hh) + ko;
  for (int kk = 0; kk < 2*Hh; kk += 32){
    bf16x8 a = *(const bf16x8*)(Ap + kk);
    #pragma unroll
    for (int j = 0; j < 4; j++){
      bf16x8 b = *(const bf16x8*)(Bp + (size_t)j*16*(2*Hh) + kk);
      acc[j] = __builtin_amdgcn_mfma_f32_16x16x32_bf16(a, b, acc[j], 0, 0, 0);
    }
  }
  int col = lane & 15, r0 = (lane >> 4) * 4;
  #pragma unroll
  for (int j = 0; j < 4; j++)
    #pragma unroll
    for (int i = 0; i < 4; i++){
      int m = mt*16 + r0 + i;
      int n = n0 + j*16 + col;
      attn_hidden[(size_t)m * Hh + n] = f2bf(tanhf(acc[j][i] + bc[n]));
    }
}

// ---------------- output = attn_hidden @ h2o_W^T + h2o_b  (M=2048,N=32000,K=1024) ----------------
__global__ __launch_bounds__(256) void k_h2o(
    const short* __restrict__ ah, const short* __restrict__ Wo,
    const float* __restrict__ bo, float* __restrict__ out)
{
  int w = blockIdx.x * 4 + (threadIdx.x >> 6);   // 64000 waves
  int lane = threadIdx.x & 63;
  int ng = w / 128;                              // 0..499  (m-fastest for L2 reuse of B)
  int mt = w % 128;
  int n0 = ng * 64;
  int ra = lane & 15, ko = (lane >> 4) * 8;
  f32x4 acc[4] = {{0,0,0,0},{0,0,0,0},{0,0,0,0},{0,0,0,0}};
  const short* Ap = ah + (size_t)(mt*16 + ra) * Hh + ko;
  const short* Bp = Wo + (size_t)(n0    + ra) * Hh + ko;
  for (int kk = 0; kk < Hh; kk += 32){
    bf16x8 a = *(const bf16x8*)(Ap + kk);
    #pragma unroll
    for (int j = 0; j < 4; j++){
      bf16x8 b = *(const bf16x8*)(Bp + (size_t)j*16*Hh + kk);
      acc[j] = __builtin_amdgcn_mfma_f32_16x16x32_bf16(a, b, acc[j], 0, 0, 0);
    }
  }
  int col = lane & 15, r0 = (lane >> 4) * 4;
  #pragma unroll
  for (int j = 0; j < 4; j++)
    #pragma unroll
    for (int i = 0; i < 4; i++){
      int m = mt*16 + r0 + i;
      int n = n0 + j*16 + col;
      out[(size_t)m * Vv + n] = acc[j][i] + bo[n];
    }
}

// ---------------- final hN / cN copy ----------------
__global__ __launch_bounds__(256) void k_final(
    const float* __restrict__ rnn_out, const float* __restrict__ c, float* __restrict__ out)
{
  int i = blockIdx.x * 256 + threadIdx.x;
  if (i >= Bb * Hh) return;
  out[(size_t)Mm * Vv + i]           = rnn_out[(size_t)(Tt-1)*Bb*Hh + i];
  out[(size_t)Mm * Vv + Bb*Hh + i]   = c[i];
}

extern "C" void kernel_launch(void* const* d_in, const int* in_sizes, int n_in,
                              void* d_out, int out_size, void* d_ws, size_t ws_size,
                              hipStream_t stream) {
  const int*   x         = (const int*)  d_in[0];
  const int*   src_len   = (const int*)  d_in[1];
  const int*   lang_idx  = (const int*)  d_in[2];
  const float* h0        = (const float*)d_in[3];
  const float* c0        = (const float*)d_in[4];
  const float* src       = (const float*)d_in[5];
  const float* vocab     = (const float*)d_in[6];
  const float* lang_emb  = (const float*)d_in[7];
  const float* Wih       = (const float*)d_in[8];
  const float* bih       = (const float*)d_in[9];
  const float* Whh       = (const float*)d_in[10];
  const float* bhh       = (const float*)d_in[11];
  const float* Wbih      = (const float*)d_in[12];
  const float* bbih      = (const float*)d_in[13];
  const float* Wbhh      = (const float*)d_in[14];
  const float* bbhh      = (const float*)d_in[15];
  const float* c2hW      = (const float*)d_in[16];
  const float* c2hb      = (const float*)d_in[17];
  const float* h2oW      = (const float*)d_in[18];
  const float* h2ob      = (const float*)d_in[19];
  float* out = (float*)d_out;

  char* ws = (char*)d_ws;
  short* w_ih   = (short*)(ws + 0);            // 4,194,304 B
  short* w_hh   = (short*)(ws + 4194304);      // 8,388,608 B
  short* c2hWb  = (short*)(ws + 12582912);     // 4,194,304 B
  short* h2oWb  = (short*)(ws + 16777216);     // 65,536,000 B
  float* b_tot  = (float*)(ws + 82313216);     // 16,384 B
  short* emb    = (short*)(ws + 82329600);     // 2,097,152 B
  float* Gx     = (float*)(ws + 84426752);     // 33,554,432 B
  short* hb0    = (short*)(ws + 117981184);    // 131,072 B
  short* hb1    = (short*)(ws + 118112256);    // 131,072 B
  float* cbuf   = (float*)(ws + 118243328);    // 262,144 B
  float* rnn    = (float*)(ws + 118505472);    // 8,388,608 B
  short* concat = (short*)(ws + 126894080);    // 8,388,608 B
  float* attn   = (float*)(ws + 135282688);    // 524,288 B
  short* ah     = (short*)(ws + 135806976);    // 4,194,304 B

  // hypernet + conversions + embedding (independent, all on stream)
  k_hyper_w<<<24576, 256, 0, stream>>>(Wih, bih, Whh, bhh, lang_emb, lang_idx, w_ih, w_hh);
  k_hyper_b<<<16, 256, 0, stream>>>(Wbih, bbih, Wbhh, bbhh, lang_emb, lang_idx, b_tot);
  k_embed<<<1024, 256, 0, stream>>>(x, vocab, emb);
  k_f2bf<<<2048, 256, 0, stream>>>(c2hW, c2hWb, (long)Hh*2*Hh/4);
  k_f2bf<<<32000, 256, 0, stream>>>(h2oW, h2oWb, (long)Vv*Hh/4);
  k_init_hc<<<256, 256, 0, stream>>>(h0, c0, hb0, cbuf);

  // x-path gates for all timesteps
  k_xgates<<<2048, 256, 0, stream>>>(emb, w_ih, b_tot, Gx);

  // sequential LSTM scan
  short* hbuf[2] = { hb0, hb1 };
  for (int t = 0; t < Tt; t++){
    k_step<<<256, 256, 0, stream>>>(t, hbuf[t & 1], w_hh, Gx, cbuf,
                                    hbuf[(t + 1) & 1], rnn, concat);
  }

  // attention
  k_scores<<<Tt*Bb, 64, 0, stream>>>(rnn, src, src_len, attn);
  k_context<<<256, 256, 0, stream>>>(attn, src, concat);

  // projections
  k_c2h<<<512, 256, 0, stream>>>(concat, c2hWb, c2hb, ah);
  k_h2o<<<16000, 256, 0, stream>>>(ah, h2oWb, h2ob, out);

  // hN, cN
  k_final<<<256, 256, 0, stream>>>(rnn, cbuf, out);
}

// Round 3
// 810.101 us; speedup vs baseline: 2.1899x; 2.1899x over previous
//
#include <hip/hip_runtime.h>
#include <math.h>

#define Tt 32
#define Bb 64
#define Ss 64
#define Ee 512
#define Hh 1024
#define Vv 32000
#define LEc 32
#define G4H 4096
#define Mm 2048   // T*B rows

typedef __bf16 bf16x8 __attribute__((ext_vector_type(8)));
typedef float f32x4 __attribute__((ext_vector_type(4)));
typedef short short4v __attribute__((ext_vector_type(4)));

__device__ __forceinline__ short f2bf(float f){
  unsigned u = __builtin_bit_cast(unsigned, f);
  u += 0x7fffu + ((u >> 16) & 1u);
  return (short)(u >> 16);
}

__device__ __forceinline__ void gl_lds16(const short* g, short* l){
  __builtin_amdgcn_global_load_lds((const __attribute__((address_space(1))) void*)g,
                                   (__attribute__((address_space(3))) void*)l, 16, 0, 0);
}

// ---------------- hypernet: w_ih / w_hh generation (bf16 out) ----------------
__global__ __launch_bounds__(256) void k_hyper_w(
    const float* __restrict__ Wih, const float* __restrict__ bihv,
    const float* __restrict__ Whh, const float* __restrict__ bhhv,
    const float* __restrict__ lang_embed, const int* __restrict__ lang_idx,
    short* __restrict__ w_ih, short* __restrict__ w_hh)
{
  const long NIH = (long)G4H * Ee;              // 2,097,152 rows
  const long NALL = NIH + (long)G4H * Hh;       // + 4,194,304 rows
  long r = (long)blockIdx.x * 256 + threadIdx.x;
  if (r >= NALL) return;
  const float4* el4 = (const float4*)(lang_embed + (size_t)lang_idx[0] * LEc);
  float4 e[8];
  #pragma unroll
  for (int j = 0; j < 8; j++) e[j] = el4[j];
  const float4* W4; float bb; short* outp;
  if (r < NIH){ W4 = (const float4*)(Wih + r * LEc); bb = bihv[r]; outp = w_ih + r; }
  else { long rr = r - NIH; W4 = (const float4*)(Whh + rr * LEc); bb = bhhv[rr]; outp = w_hh + rr; }
  float acc = bb;
  #pragma unroll
  for (int j = 0; j < 8; j++){
    float4 w = W4[j];
    acc += w.x*e[j].x + w.y*e[j].y + w.z*e[j].z + w.w*e[j].w;
  }
  *outp = f2bf(acc);
}

// ---------------- hypernet: combined bias b_ih + b_hh (f32) ----------------
__global__ __launch_bounds__(256) void k_hyper_b(
    const float* __restrict__ Wbih, const float* __restrict__ bbih,
    const float* __restrict__ Wbhh, const float* __restrict__ bbhh,
    const float* __restrict__ lang_embed, const int* __restrict__ lang_idx,
    float* __restrict__ b_total)
{
  int u = blockIdx.x * 256 + threadIdx.x;
  if (u >= G4H) return;
  const float* el = lang_embed + (size_t)lang_idx[0] * LEc;
  float acc = bbih[u] + bbhh[u];
  #pragma unroll
  for (int j = 0; j < LEc; j++)
    acc += (Wbih[(size_t)u*LEc + j] + Wbhh[(size_t)u*LEc + j]) * el[j];
  b_total[u] = acc;
}

// ---------------- embedding gather -> bf16 ----------------
__global__ __launch_bounds__(256) void k_embed(
    const int* __restrict__ x, const float* __restrict__ vocab, short* __restrict__ emb)
{
  int tid = blockIdx.x * 256 + threadIdx.x;      // Mm*Ee/4 threads
  if (tid >= Mm * Ee / 4) return;
  int row = tid / (Ee / 4);
  int j4 = (tid % (Ee / 4)) * 4;
  int tok = x[row];
  float4 v = *(const float4*)(vocab + (size_t)tok * Ee + j4);
  short4v o = { f2bf(v.x), f2bf(v.y), f2bf(v.z), f2bf(v.w) };
  *(short4v*)(emb + (size_t)row * Ee + j4) = o;
}

// ---------------- generic f32 -> bf16 convert ----------------
__global__ __launch_bounds__(256) void k_f2bf(const float* __restrict__ in, short* __restrict__ out, long n4)
{
  long i = (long)blockIdx.x * 256 + threadIdx.x;
  if (i >= n4) return;
  float4 v = ((const float4*)in)[i];
  short4v o = { f2bf(v.x), f2bf(v.y), f2bf(v.z), f2bf(v.w) };
  ((short4v*)out)[i] = o;
}

// ---------------- tiled MFMA GEMM: C[M][N] = A[M][K] @ B[N][K]^T (+bias, epilogue) ----
// m97 structure: 128x128 tile, 4 waves (2x2), BK=32, global_load_lds width=16,
// 2-barrier K-loop. MODE 0: f32 out = acc + bias. MODE 1: bf16 out = tanh(acc+bias).
template<int M, int N, int K, int MODE>
__global__ __launch_bounds__(256) void k_gemm(
    const short* __restrict__ A, const short* __restrict__ B,
    const float* __restrict__ bias, void* __restrict__ Cv)
{
  __shared__ short lA[4096];   // 128 rows x 32 cols
  __shared__ short lB[4096];
  const int nwg = (M/128)*(N/128);           // all instantiations: nwg % 8 == 0
  int xcd = blockIdx.x & 7, pos = blockIdx.x >> 3;
  int wg = xcd * (nwg >> 3) + pos;           // XCD-contiguous chunks
  const int MT = M/128;
  int mt = wg % MT;                          // m fastest -> B-panel L2 reuse
  int nt = wg / MT;

  int t = threadIdx.x;
  int wave = t >> 6, lane = t & 63;
  int wm = wave >> 1, wn = wave & 1;
  int tr = t >> 2;            // staging row 0..63
  int tc = (t & 3) * 8;       // staging col elems

  const short* Agp = A + (size_t)(mt*128)*K;
  const short* Bgp = B + (size_t)(nt*128)*K;

  f32x4 acc[4][4];
  #pragma unroll
  for (int i = 0; i < 4; i++)
    #pragma unroll
    for (int j = 0; j < 4; j++) acc[i][j] = (f32x4){0.f,0.f,0.f,0.f};

  int ra = lane & 15, ko = (lane >> 4) * 8;

  for (int k0 = 0; k0 < K; k0 += 32){
    // stage A/B tiles (linear LDS, per-lane global source)
    #pragma unroll
    for (int q2 = 0; q2 < 2; q2++){
      gl_lds16(Agp + (size_t)(q2*64 + tr)*K + k0 + tc, &lA[q2*2048 + wave*512]);
      gl_lds16(Bgp + (size_t)(q2*64 + tr)*K + k0 + tc, &lB[q2*2048 + wave*512]);
    }
    __syncthreads();   // drains vmcnt(0) + barrier
    bf16x8 av[4], bv[4];
    #pragma unroll
    for (int i = 0; i < 4; i++){
      av[i] = *(const bf16x8*)&lA[(wm*64 + i*16 + ra)*32 + ko];
      bv[i] = *(const bf16x8*)&lB[(wn*64 + i*16 + ra)*32 + ko];
    }
    #pragma unroll
    for (int i = 0; i < 4; i++)
      #pragma unroll
      for (int j = 0; j < 4; j++)
        acc[i][j] = __builtin_amdgcn_mfma_f32_16x16x32_bf16(av[i], bv[j], acc[i][j], 0, 0, 0);
    __syncthreads();   // protect LDS before next stage
  }

  int col = lane & 15, r0 = (lane >> 4) * 4;
  #pragma unroll
  for (int i = 0; i < 4; i++)
    #pragma unroll
    for (int j = 0; j < 4; j++)
      #pragma unroll
      for (int q = 0; q < 4; q++){
        int m = mt*128 + wm*64 + i*16 + r0 + q;
        int n = nt*128 + wn*64 + j*16 + col;
        float v = acc[i][j][q] + bias[n];
        if (MODE == 0) ((float*)Cv)[(size_t)m * N + n] = v;
        else           ((short*)Cv)[(size_t)m * N + n] = f2bf(tanhf(v));
      }
}

// ---------------- init h (bf16) and c (f32) ----------------
__global__ __launch_bounds__(256) void k_init_hc(
    const float* __restrict__ h0, const float* __restrict__ c0,
    short* __restrict__ hbf, float* __restrict__ c)
{
  int i = blockIdx.x * 256 + threadIdx.x;
  if (i >= Bb * Hh) return;
  hbf[i] = f2bf(h0[i]);
  c[i] = c0[i];
}

// ---------------- one LSTM step: gates = Gx[t] + h @ w_hh^T ; elementwise ----------------
__global__ __launch_bounds__(256) void k_step(
    int t, const short* __restrict__ h_in, const short* __restrict__ w_hh,
    const float* __restrict__ Gx, float* __restrict__ c,
    short* __restrict__ h_out, float* __restrict__ rnn_out, short* __restrict__ concat)
{
  __shared__ float red[4][4][16][16];
  int mt = blockIdx.x >> 6;          // 0..3
  int n0 = (blockIdx.x & 63) * 16;   // 0..1008
  int wv = threadIdx.x >> 6;         // k-chunk 0..3
  int lane = threadIdx.x & 63;
  int ra = lane & 15, ko = (lane >> 4) * 8;
  f32x4 acc[4] = {{0,0,0,0},{0,0,0,0},{0,0,0,0},{0,0,0,0}};
  const short* Ap = h_in + (size_t)(mt*16 + ra) * Hh + wv*256 + ko;
  const short* Bp = w_hh + (size_t)(n0    + ra) * Hh + wv*256 + ko;
  #pragma unroll
  for (int kk = 0; kk < 256; kk += 32){
    bf16x8 a = *(const bf16x8*)(Ap + kk);
    #pragma unroll
    for (int g = 0; g < 4; g++){
      bf16x8 b = *(const bf16x8*)(Bp + (size_t)g*Hh*Hh + kk);
      acc[g] = __builtin_amdgcn_mfma_f32_16x16x32_bf16(a, b, acc[g], 0, 0, 0);
    }
  }
  int col = lane & 15, r0 = (lane >> 4) * 4;
  #pragma unroll
  for (int g = 0; g < 4; g++)
    #pragma unroll
    for (int i = 0; i < 4; i++)
      red[wv][g][r0 + i][col] = acc[g][i];
  __syncthreads();

  int r  = threadIdx.x >> 4;   // 0..15
  int cc = threadIdx.x & 15;
  int b  = mt*16 + r;
  int u  = n0 + cc;
  float gate[4];
  #pragma unroll
  for (int g = 0; g < 4; g++){
    float s = Gx[((size_t)t*Bb + b) * G4H + g*Hh + u];
    #pragma unroll
    for (int w2 = 0; w2 < 4; w2++) s += red[w2][g][r][cc];
    gate[g] = s;
  }
  float ig = 1.f / (1.f + expf(-gate[0]));
  float fg = 1.f / (1.f + expf(-gate[1]));
  float gg = tanhf(gate[2]);
  float og = 1.f / (1.f + expf(-gate[3]));
  size_t bu = (size_t)b * Hh + u;
  float cn = fg * c[bu] + ig * gg;
  c[bu] = cn;
  float hn = og * tanhf(cn);
  h_out[bu] = f2bf(hn);
  size_t row = (size_t)t * Bb + b;
  rnn_out[row * Hh + u] = hn;
  concat[row * (2*Hh) + Hh + u] = f2bf(hn);
}

// ---------------- scores + mask + softmax (wave per (t,b), lane = s) ----------------
__global__ __launch_bounds__(64) void k_scores(
    const float* __restrict__ rnn_out, const float* __restrict__ src,
    const int* __restrict__ src_len, float* __restrict__ attn)
{
  int t = blockIdx.x >> 6;
  int b = blockIdx.x & 63;
  int s = threadIdx.x;
  const float4* rp = (const float4*)(rnn_out + ((size_t)t*Bb + b) * Hh);
  const float4* sp = (const float4*)(src     + ((size_t)s*Bb + b) * Hh);
  float acc = 0.f;
  #pragma unroll 4
  for (int i = 0; i < Hh/4; i++){
    float4 rv = rp[i], sv = sp[i];
    acc += rv.x*sv.x + rv.y*sv.y + rv.z*sv.z + rv.w*sv.w;
  }
  if (s >= src_len[b]) acc = -1e30f;
  float mx = acc;
  for (int o = 32; o; o >>= 1) mx = fmaxf(mx, __shfl_xor(mx, o, 64));
  float p = expf(acc - mx);
  float sum = p;
  for (int o = 32; o; o >>= 1) sum += __shfl_xor(sum, o, 64);
  attn[((size_t)t*Bb + b) * Ss + s] = p / sum;
}

// ---------------- context = attn @ src  -> concat[:, 0:H] (bf16) ----------------
__global__ __launch_bounds__(256) void k_context(
    const float* __restrict__ attn, const float* __restrict__ src, short* __restrict__ concat)
{
  __shared__ float sat[8][64];
  int b  = blockIdx.x & 63;
  int t0 = (blockIdx.x >> 6) * 8;
  int tid = threadIdx.x;
  for (int i = tid; i < 8*64; i += 256){
    int ti = i >> 6, s = i & 63;
    sat[ti][s] = attn[((size_t)(t0 + ti)*Bb + b) * Ss + s];
  }
  __syncthreads();
  int h0 = tid * 4;
  float4 acc[8];
  #pragma unroll
  for (int i = 0; i < 8; i++) acc[i] = make_float4(0.f, 0.f, 0.f, 0.f);
  for (int s = 0; s < Ss; s++){
    float4 sv = *(const float4*)(src + ((size_t)s*Bb + b) * Hh + h0);
    #pragma unroll
    for (int i = 0; i < 8; i++){
      float a = sat[i][s];
      acc[i].x += a*sv.x; acc[i].y += a*sv.y; acc[i].z += a*sv.z; acc[i].w += a*sv.w;
    }
  }
  #pragma unroll
  for (int i = 0; i < 8; i++){
    size_t row = (size_t)(t0 + i)*Bb + b;
    short4v o = { f2bf(acc[i].x), f2bf(acc[i].y), f2bf(acc[i].z), f2bf(acc[i].w) };
    *(short4v*)(concat + row * (2*Hh) + h0) = o;
  }
}

// ---------------- final hN / cN copy ----------------
__global__ __launch_bounds__(256) void k_final(
    const float* __restrict__ rnn_out, const float* __restrict__ c, float* __restrict__ out)
{
  int i = blockIdx.x * 256 + threadIdx.x;
  if (i >= Bb * Hh) return;
  out[(size_t)Mm * Vv + i]           = rnn_out[(size_t)(Tt-1)*Bb*Hh + i];
  out[(size_t)Mm * Vv + Bb*Hh + i]   = c[i];
}

extern "C" void kernel_launch(void* const* d_in, const int* in_sizes, int n_in,
                              void* d_out, int out_size, void* d_ws, size_t ws_size,
                              hipStream_t stream) {
  const int*   x         = (const int*)  d_in[0];
  const int*   src_len   = (const int*)  d_in[1];
  const int*   lang_idx  = (const int*)  d_in[2];
  const float* h0        = (const float*)d_in[3];
  const float* c0        = (const float*)d_in[4];
  const float* src       = (const float*)d_in[5];
  const float* vocab     = (const float*)d_in[6];
  const float* lang_emb  = (const float*)d_in[7];
  const float* Wih       = (const float*)d_in[8];
  const float* bih       = (const float*)d_in[9];
  const float* Whh       = (const float*)d_in[10];
  const float* bhh       = (const float*)d_in[11];
  const float* Wbih      = (const float*)d_in[12];
  const float* bbih      = (const float*)d_in[13];
  const float* Wbhh      = (const float*)d_in[14];
  const float* bbhh      = (const float*)d_in[15];
  const float* c2hW      = (const float*)d_in[16];
  const float* c2hb      = (const float*)d_in[17];
  const float* h2oW      = (const float*)d_in[18];
  const float* h2ob      = (const float*)d_in[19];
  float* out = (float*)d_out;

  char* ws = (char*)d_ws;
  short* w_ih   = (short*)(ws + 0);            // 4,194,304 B
  short* w_hh   = (short*)(ws + 4194304);      // 8,388,608 B
  short* c2hWb  = (short*)(ws + 12582912);     // 4,194,304 B
  short* h2oWb  = (short*)(ws + 16777216);     // 65,536,000 B
  float* b_tot  = (float*)(ws + 82313216);     // 16,384 B
  short* emb    = (short*)(ws + 82329600);     // 2,097,152 B
  float* Gx     = (float*)(ws + 84426752);     // 33,554,432 B
  short* hb0    = (short*)(ws + 117981184);    // 131,072 B
  short* hb1    = (short*)(ws + 118112256);    // 131,072 B
  float* cbuf   = (float*)(ws + 118243328);    // 262,144 B
  float* rnn    = (float*)(ws + 118505472);    // 8,388,608 B
  short* concat = (short*)(ws + 126894080);    // 8,388,608 B
  float* attn   = (float*)(ws + 135282688);    // 524,288 B
  short* ah     = (short*)(ws + 135806976);    // 4,194,304 B

  // hypernet + conversions + embedding (independent, all on stream)
  k_hyper_w<<<24576, 256, 0, stream>>>(Wih, bih, Whh, bhh, lang_emb, lang_idx, w_ih, w_hh);
  k_hyper_b<<<16, 256, 0, stream>>>(Wbih, bbih, Wbhh, bbhh, lang_emb, lang_idx, b_tot);
  k_embed<<<1024, 256, 0, stream>>>(x, vocab, emb);
  k_f2bf<<<2048, 256, 0, stream>>>(c2hW, c2hWb, (long)Hh*2*Hh/4);
  k_f2bf<<<32000, 256, 0, stream>>>(h2oW, h2oWb, (long)Vv*Hh/4);
  k_init_hc<<<256, 256, 0, stream>>>(h0, c0, hb0, cbuf);

  // x-path gates for all timesteps: Gx = emb @ w_ih^T + b_total
  k_gemm<Mm, G4H, Ee, 0><<<(Mm/128)*(G4H/128), 256, 0, stream>>>(emb, w_ih, b_tot, Gx);

  // sequential LSTM scan
  short* hbuf[2] = { hb0, hb1 };
  for (int t = 0; t < Tt; t++){
    k_step<<<256, 256, 0, stream>>>(t, hbuf[t & 1], w_hh, Gx, cbuf,
                                    hbuf[(t + 1) & 1], rnn, concat);
  }

  // attention
  k_scores<<<Tt*Bb, 64, 0, stream>>>(rnn, src, src_len, attn);
  k_context<<<256, 256, 0, stream>>>(attn, src, concat);

  // projections
  k_gemm<Mm, Hh, 2*Hh, 1><<<(Mm/128)*(Hh/128), 256, 0, stream>>>(concat, c2hWb, c2hb, ah);
  k_gemm<Mm, Vv, Hh, 0><<<(Mm/128)*(Vv/128), 256, 0, stream>>>(ah, h2oWb, h2ob, out);

  // hN, cN
  k_final<<<256, 256, 0, stream>>>(rnn, cbuf, out);
}